// Round 3
// baseline (97.375 us; speedup 1.0000x reference)
//
#include <hip/hip_runtime.h>

#define HIDDEN 14336
#define NCHUNK 28

// Fixed 28x28 Hadamard sign matrix from the reference (row-major, '+' = +1).
// Structure (verified): H28 = [[C+I, C-I],[C-I, -(C+I)]], C = 14x14 zero-diag
// conference matrix, C[i][j] = HS[i][j] for i,j<14, i!=j.
constexpr char HS[28][29] = {
    "++++++++++++++-+++++++++++++",
    "+++-++----++-++-+-++----++-+",
    "++++-++----++-++-+-++----++-",
    "+-+++-++----+++-+-+-++----++",
    "++-+++-++----+++-+-+-++----+",
    "+++-+++-++----+++-+-+-++----",
    "+-++-+++-++---+-++-+-+-++---",
    "+--++-+++-++--+--++-+-+-++--",
    "+---++-+++-++-+---++-+-+-++-",
    "+----++-+++-+++----++-+-+-++",
    "++----++-+++-+++----++-+-+-+",
    "+++----++-+++-+++----++-+-+-",
    "+-++----++-++++-++----++-+-+",
    "++-++----++-++++-++----++-+-",
    "-+++++++++++++--------------",
    "+-+-++----++-+---+--++++--+-",
    "++-+-++----++-----+--++++--+",
    "+-+-+-++----++-+---+--++++--",
    "++-+-+-++----+--+---+--++++-",
    "+++-+-+-++-------+---+--++++",
    "+-++-+-+-++----+--+---+--+++",
    "+--++-+-+-++---++--+---+--++",
    "+---++-+-+-++--+++--+---+--+",
    "+----++-+-+-++-++++--+---+--",
    "++----++-+-+-+--++++--+---+-",
    "+++----++-+-+----++++--+---+",
    "+-++----++-+-+-+--++++--+---",
    "++-++----++-+---+--++++--+--",
};

// 8-point FWHT on 8 register references (strides folded by caller).
static __device__ __forceinline__ void fwht8r(float& v0, float& v1, float& v2, float& v3,
                                              float& v4, float& v5, float& v6, float& v7) {
    float a0 = v0 + v1, a1 = v0 - v1, a2 = v2 + v3, a3 = v2 - v3;
    float a4 = v4 + v5, a5 = v4 - v5, a6 = v6 + v7, a7 = v6 - v7;
    float b0 = a0 + a2, b2 = a0 - a2, b1 = a1 + a3, b3 = a1 - a3;
    float b4 = a4 + a6, b6 = a4 - a6, b5 = a5 + a7, b7 = a5 - a7;
    v0 = b0 + b4; v4 = b0 - b4; v1 = b1 + b5; v5 = b1 - b5;
    v2 = b2 + b6; v6 = b2 - b6; v3 = b3 + b7; v7 = b3 - b7;
}

static __device__ __forceinline__ float2 f2add(float2 a, float2 b) {
    return make_float2(a.x + b.x, a.y + b.y);
}
static __device__ __forceinline__ float2 f2sub(float2 a, float2 b) {
    return make_float2(a.x - b.x, a.y - b.y);
}
static __device__ __forceinline__ float2 f2fma(float k, float2 a, float2 b) {
    return make_float2(fmaf(k, a.x, b.x), fmaf(k, a.y, b.y));
}

// LDS layout: element i of chunk c, digits i = b0 + 8*b1 + 64*b2, lives in
// tile T = c*8 + b0 (64 floats) at in-tile offset o = b1 + 8*b2, placed at
// byte-slot swizzle: pos(o,T) = (o&3) + 4*((o>>2) ^ (T&15)).
// All phases access full 64-float runs -> bank-uniform, no padding.
__global__ __launch_bounds__(256) void quarot_kernel(const float* __restrict__ X,
                                                     float* __restrict__ Y) {
    __shared__ float s[HIDDEN];
    const int tid = threadIdx.x;
    const size_t row = blockIdx.x;
    const float* __restrict__ xr = X + row * (size_t)HIDDEN;
    float* __restrict__ yr = Y + row * (size_t)HIDDEN;
    const float scale = 1.0f / sqrtf((float)HIDDEN);  // compile-time folded

    // ---- Phase 1: 32-float tasks. Load, scale, FWHT8 over b0, b128-write
    // into transposed+swizzled layout. 448 tasks.
    #pragma unroll
    for (int it = 0; it < 2; ++it) {
        const int a = tid + it * 256;
        if (it == 0 || tid < 192) {
            const int chunk = a >> 4;   // 16 tasks per 512-chunk
            const int gq = a & 15;      // o>>2 group for these 4 g-values
            float v[32];
            #pragma unroll
            for (int j = 0; j < 8; ++j) {
                const float4 w = *reinterpret_cast<const float4*>(xr + a * 32 + j * 4);
                v[j * 4 + 0] = w.x * scale; v[j * 4 + 1] = w.y * scale;
                v[j * 4 + 2] = w.z * scale; v[j * 4 + 3] = w.w * scale;
            }
            #pragma unroll
            for (int j = 0; j < 4; ++j)
                fwht8r(v[8 * j + 0], v[8 * j + 1], v[8 * j + 2], v[8 * j + 3],
                       v[8 * j + 4], v[8 * j + 5], v[8 * j + 6], v[8 * j + 7]);
            #pragma unroll
            for (int b0 = 0; b0 < 8; ++b0) {
                const int T = chunk * 8 + b0;
                const int addr = T * 64 + 4 * (gq ^ (T & 15));
                *reinterpret_cast<float4*>(s + addr) =
                    make_float4(v[b0], v[8 + b0], v[16 + b0], v[24 + b0]);
            }
        }
    }
    __syncthreads();

    // ---- Phase 2: one thread per 64-float tile (224 tiles). All-register
    // FWHT8 over b1 then b2 with b128 LDS access both ways.
    if (tid < 224) {
        const int k = tid & 15;
        float* base = s + tid * 64;
        float r[64];
        #pragma unroll
        for (int q = 0; q < 16; ++q) {
            const float4 w = *reinterpret_cast<const float4*>(base + 4 * (q ^ k));
            r[4 * q + 0] = w.x; r[4 * q + 1] = w.y; r[4 * q + 2] = w.z; r[4 * q + 3] = w.w;
        }
        #pragma unroll
        for (int b2 = 0; b2 < 8; ++b2)   // FWHT over b1 (low digit of o)
            fwht8r(r[8 * b2 + 0], r[8 * b2 + 1], r[8 * b2 + 2], r[8 * b2 + 3],
                   r[8 * b2 + 4], r[8 * b2 + 5], r[8 * b2 + 6], r[8 * b2 + 7]);
        #pragma unroll
        for (int b1 = 0; b1 < 8; ++b1)   // FWHT over b2 (high digit of o)
            fwht8r(r[b1], r[b1 + 8], r[b1 + 16], r[b1 + 24],
                   r[b1 + 32], r[b1 + 40], r[b1 + 48], r[b1 + 56]);
        #pragma unroll
        for (int q = 0; q < 16; ++q)
            *reinterpret_cast<float4*>(base + 4 * (q ^ k)) =
                make_float4(r[4 * q + 0], r[4 * q + 1], r[4 * q + 2], r[4 * q + 3]);
    }
    __syncthreads();

    // ---- Phase 3: H28 mix via conference-matrix CSE over column pairs
    // (c, c+8), which are adjacent in the transposed layout (b64 reads).
    {
        const int b0 = tid & 7;
        const int hb1 = (tid >> 3) & 3;
        const int b2 = tid >> 5;
        const int c = b0 + 16 * hb1 + 64 * b2;
        const int olow = 2 * (hb1 & 1);          // o & 3 (even)
        const int ohigh = (hb1 >> 1) + 2 * b2;   // o >> 2
        const int offE = olow + 4 * (ohigh ^ b0);        // chunks with even j
        const int offO = olow + 4 * (ohigh ^ (b0 + 8));  // chunks with odd j

        float2 u[14], d[14];
        #pragma unroll
        for (int j = 0; j < 14; ++j) {
            const int offj = (j & 1) ? offO : offE;  // j and j+14 share parity
            const float2 a = *reinterpret_cast<const float2*>(s + (j * 8 + b0) * 64 + offj);
            const float2 b = *reinterpret_cast<const float2*>(s + ((j + 14) * 8 + b0) * 64 + offj);
            u[j] = f2add(a, b);
            d[j] = f2sub(a, b);
        }
        // Pairwise-tree totals
        float2 su0 = f2add(f2add(u[0], u[1]), f2add(u[2], u[3]));
        float2 su1 = f2add(f2add(u[4], u[5]), f2add(u[6], u[7]));
        float2 su2 = f2add(f2add(u[8], u[9]), f2add(u[10], u[11]));
        float2 su3 = f2add(u[12], u[13]);
        const float2 Su = f2add(f2add(su0, su1), f2add(su2, su3));
        float2 sd0 = f2add(f2add(d[0], d[1]), f2add(d[2], d[3]));
        float2 sd1 = f2add(f2add(d[4], d[5]), f2add(d[6], d[7]));
        float2 sd2 = f2add(f2add(d[8], d[9]), f2add(d[10], d[11]));
        float2 sd3 = f2add(d[12], d[13]);
        const float2 Sd = f2add(f2add(sd0, sd1), f2add(sd2, sd3));

        #pragma unroll
        for (int i = 0; i < 14; ++i) {
            float2 nu = make_float2(0.0f, 0.0f);
            float2 nd = make_float2(0.0f, 0.0f);
            #pragma unroll
            for (int j = 0; j < 14; ++j) {
                if (j != i && HS[i][j] == '-') {   // compile-time folded
                    nu = f2add(nu, u[j]);
                    nd = f2add(nd, d[j]);
                }
            }
            const float2 Cu = f2fma(-2.0f, nu, f2sub(Su, u[i]));
            const float2 Cd = f2fma(-2.0f, nd, f2sub(Sd, d[i]));
            const float2 yt = f2add(Cu, d[i]);
            const float2 yb = f2sub(Cd, u[i]);
            yr[i * 512 + c] = yt.x;
            yr[i * 512 + c + 8] = yt.y;
            yr[(i + 14) * 512 + c] = yb.x;
            yr[(i + 14) * 512 + c + 8] = yb.y;
        }
    }
}

extern "C" void kernel_launch(void* const* d_in, const int* in_sizes, int n_in,
                              void* d_out, int out_size, void* d_ws, size_t ws_size,
                              hipStream_t stream) {
    const float* X = (const float*)d_in[0];
    float* Y = (float*)d_out;
    const int rows = in_sizes[0] / HIDDEN;  // 4096
    quarot_kernel<<<dim3(rows), dim3(256), 0, stream>>>(X, Y);
}

// Round 4
// 91.353 us; speedup vs baseline: 1.0659x; 1.0659x over previous
//
#include <hip/hip_runtime.h>

#define HIDDEN 14336

// Fixed 28x28 Hadamard sign matrix from the reference (row-major, '+' = +1).
// Structure (verified R2): H28 = [[C+I, C-I],[C-I, -(C+I)]], C = 14x14
// zero-diag conference matrix, C[i][j] = HS[i][j] for i,j<14, i!=j.
constexpr char HS[28][29] = {
    "++++++++++++++-+++++++++++++",
    "+++-++----++-++-+-++----++-+",
    "++++-++----++-++-+-++----++-",
    "+-+++-++----+++-+-+-++----++",
    "++-+++-++----+++-+-+-++----+",
    "+++-+++-++----+++-+-+-++----",
    "+-++-+++-++---+-++-+-+-++---",
    "+--++-+++-++--+--++-+-+-++--",
    "+---++-+++-++-+---++-+-+-++-",
    "+----++-+++-+++----++-+-+-++",
    "++----++-+++-+++----++-+-+-+",
    "+++----++-+++-+++----++-+-+-",
    "+-++----++-++++-++----++-+-+",
    "++-++----++-++++-++----++-+-",
    "-+++++++++++++--------------",
    "+-+-++----++-+---+--++++--+-",
    "++-+-++----++-----+--++++--+",
    "+-+-+-++----++-+---+--++++--",
    "++-+-+-++----+--+---+--++++-",
    "+++-+-+-++-------+---+--++++",
    "+-++-+-+-++----+--+---+--+++",
    "+--++-+-+-++---++--+---+--++",
    "+---++-+-+-++--+++--+---+--+",
    "+----++-+-+-++-++++--+---+--",
    "++----++-+-+-+--++++--+---+-",
    "+++----++-+-+----++++--+---+",
    "+-++----++-+-+-+--++++--+---",
    "++-++----++-+---+--++++--+--",
};

// In-lane FWHT over 16 registers (bits 0..3 of the element index).
static __device__ __forceinline__ void fwht16(float (&v)[16]) {
    #pragma unroll
    for (int h = 1; h < 16; h <<= 1) {
        #pragma unroll
        for (int i = 0; i < 16; ++i) {
            if ((i & h) == 0) {
                const float a = v[i], b = v[i | h];
                v[i] = a + b;
                v[i | h] = a - b;
            }
        }
    }
}

// Cross-lane butterfly: out_l = v_{l^m} + sign_l * v_l, sign via xor mask.
// XOR-1 / XOR-2 partners via DPP quad_perm (VALU pipe).
template <int CTRL>
static __device__ __forceinline__ float bfly_dpp(float x, int sm) {
    const int fi = __float_as_int(x);
    const int p = __builtin_amdgcn_update_dpp(fi, fi, CTRL, 0xF, 0xF, false);
    return __int_as_float(p) + __int_as_float(fi ^ sm);
}

// XOR-4 / 8 / 16 partners via ds_swizzle BitMode (intra-32-lane).
template <int PAT>
static __device__ __forceinline__ float bfly_swz(float x, int sm) {
    const int fi = __float_as_int(x);
    const int p = __builtin_amdgcn_ds_swizzle(fi, PAT);
    return __int_as_float(p) + __int_as_float(fi ^ sm);
}

// FWHT32 across the 32-lane half (bits 4..8 of the element index).
static __device__ __forceinline__ void fwht_cross32(float (&v)[16], int sm1, int sm2,
                                                    int sm4, int sm8, int sm16) {
    #pragma unroll
    for (int k = 0; k < 16; ++k) v[k] = bfly_dpp<0xB1>(v[k], sm1);   // quad_perm [1,0,3,2]
    #pragma unroll
    for (int k = 0; k < 16; ++k) v[k] = bfly_dpp<0x4E>(v[k], sm2);   // quad_perm [2,3,0,1]
    #pragma unroll
    for (int k = 0; k < 16; ++k) v[k] = bfly_swz<0x101F>(v[k], sm4);  // xor 4
    #pragma unroll
    for (int k = 0; k < 16; ++k) v[k] = bfly_swz<0x201F>(v[k], sm8);  // xor 8
    #pragma unroll
    for (int k = 0; k < 16; ++k) v[k] = bfly_swz<0x401F>(v[k], sm16); // xor 16
}

// LDS layout (per chunk, 512 floats, no padding): col c stored at
//   (c>>6)*64 + 4*(((c>>2)&15) ^ (c>>6)) + (c&3)
// XOR of the row index into the 4-float slot -> b128 writes land 4 lanes per
// bank-class (same as linear coalesced) and mix reads are 2-way (free).
__global__ __launch_bounds__(448) void quarot_kernel(const float* __restrict__ X,
                                                     float* __restrict__ Y) {
    __shared__ float s[HIDDEN];
    const int tid = threadIdx.x;
    const int l = tid & 63;
    const int w = tid >> 6;     // wave 0..6
    const int q = l & 31;       // lane within half-wave
    const int h = l >> 5;       // which half
    const int sm1 = (q & 1) ? 0x80000000 : 0;
    const int sm2 = (q & 2) ? 0x80000000 : 0;
    const int sm4 = (q & 4) ? 0x80000000 : 0;
    const int sm8 = (q & 8) ? 0x80000000 : 0;
    const int sm16 = (q & 16) ? 0x80000000 : 0;

    const float* __restrict__ xr = X + (size_t)blockIdx.x * HIDDEN;
    float* __restrict__ yr = Y + (size_t)blockIdx.x * HIDDEN;
    const float scale = 1.0f / sqrtf((float)HIDDEN);  // compile-time folded

    // Two chunk-pair tasks per wave: chunks {4w+h, 4w+2+h}.
    const int cA = 4 * w + h;
    const int cB = 4 * w + 2 + h;

    float vA[16], vB[16];
    {
        const float* pA = xr + cA * 512 + q * 16;
        const float* pB = xr + cB * 512 + q * 16;
        #pragma unroll
        for (int g = 0; g < 4; ++g) {
            const float4 a = *reinterpret_cast<const float4*>(pA + 4 * g);
            vA[4 * g + 0] = a.x * scale; vA[4 * g + 1] = a.y * scale;
            vA[4 * g + 2] = a.z * scale; vA[4 * g + 3] = a.w * scale;
        }
        #pragma unroll
        for (int g = 0; g < 4; ++g) {
            const float4 b = *reinterpret_cast<const float4*>(pB + 4 * g);
            vB[4 * g + 0] = b.x * scale; vB[4 * g + 1] = b.y * scale;
            vB[4 * g + 2] = b.z * scale; vB[4 * g + 3] = b.w * scale;
        }
    }

    fwht16(vA);
    fwht_cross32(vA, sm1, sm2, sm4, sm8, sm16);
    {
        const int r = q >> 2;
        #pragma unroll
        for (int g = 0; g < 4; ++g) {
            const int slot = ((4 * q + g) & 15) ^ r;
            *reinterpret_cast<float4*>(s + cA * 512 + r * 64 + 4 * slot) =
                make_float4(vA[4 * g + 0], vA[4 * g + 1], vA[4 * g + 2], vA[4 * g + 3]);
        }
    }

    fwht16(vB);
    fwht_cross32(vB, sm1, sm2, sm4, sm8, sm16);
    {
        const int r = q >> 2;
        #pragma unroll
        for (int g = 0; g < 4; ++g) {
            const int slot = ((4 * q + g) & 15) ^ r;
            *reinterpret_cast<float4*>(s + cB * 512 + r * 64 + 4 * slot) =
                make_float4(vB[4 * g + 0], vB[4 * g + 1], vB[4 * g + 2], vB[4 * g + 3]);
        }
    }

    __syncthreads();

    // ---- Mix phase: conference-matrix CSE per column; coalesced stores. ----
    // Wave w handles cols 64w..64w+63 (one LDS row-region per wave); wave 0
    // additionally handles cols 448..511.
    for (int c = tid; c < 512; c += 448) {
        const int rr = c >> 6;
        const int boff = rr * 64 + 4 * (((c >> 2) & 15) ^ rr) + (c & 3);
        float u[14], d[14];
        #pragma unroll
        for (int j = 0; j < 14; ++j) {
            const float a = s[j * 512 + boff];
            const float b = s[(j + 14) * 512 + boff];
            u[j] = a + b;
            d[j] = a - b;
        }
        const float Su = (((u[0] + u[1]) + (u[2] + u[3])) + ((u[4] + u[5]) + (u[6] + u[7]))) +
                         (((u[8] + u[9]) + (u[10] + u[11])) + (u[12] + u[13]));
        const float Sd = (((d[0] + d[1]) + (d[2] + d[3])) + ((d[4] + d[5]) + (d[6] + d[7]))) +
                         (((d[8] + d[9]) + (d[10] + d[11])) + (d[12] + d[13]));
        #pragma unroll
        for (int i = 0; i < 14; ++i) {
            float nu = 0.0f, nd = 0.0f;
            #pragma unroll
            for (int j = 0; j < 14; ++j) {
                if (j != i && HS[i][j] == '-') {  // compile-time folded
                    nu += u[j];
                    nd += d[j];
                }
            }
            const float Cu = fmaf(-2.0f, nu, Su - u[i]);
            const float Cd = fmaf(-2.0f, nd, Sd - d[i]);
            yr[i * 512 + c] = Cu + d[i];
            yr[(i + 14) * 512 + c] = Cd - u[i];
        }
    }
}

extern "C" void kernel_launch(void* const* d_in, const int* in_sizes, int n_in,
                              void* d_out, int out_size, void* d_ws, size_t ws_size,
                              hipStream_t stream) {
    const float* X = (const float*)d_in[0];
    float* Y = (float*)d_out;
    const int rows = in_sizes[0] / HIDDEN;  // 4096
    quarot_kernel<<<dim3(rows), dim3(448), 0, stream>>>(X, Y);
}